// Round 16
// baseline (165.008 us; speedup 1.0000x reference)
//
#include <hip/hip_runtime.h>
#include <math.h>

// Problem: scores = q[2048x768] @ p[16384x768]^T (fp32 in), per-query
// rank-of-target + log-softmax CE + Gaussian rank weight -> mean (scalar).
// R17: full 8-phase schedule (T3+T4+T5, m201 template, fp8-adapted).
// R16 post-mortem: 2 blocks/CU resident -> NULL (62.2 us) -> co-residency
// doesn't cover the stall. R12-R16 sum: conflicts 0, interleave null,
// occupancy null, all pipes <=33% => the m233 2-phase structural plateau
// (stage+vmcnt+barrier ~72% overhead; removing one element never helps).
// Escape = 8-phase: per phase {ds-read quadrant || stage 1 load || bar ||
// lgkmcnt(0) || 16 MFMA (setprio) || bar}; vmcnt counted ONCE per K-tile.
//  - 512 thr / 8 waves (2Mx4N), per-wave 128x64 out: acc[8][4] f32x4
//    (~175 VGPR, 2 waves/SIMD, 1 block/CU).
//  - LDS: 3 bufs x (A 16KB + B 16KB) = 96KB + st 1KB. Unit = 16 rows x
//    64 k-bytes (1KB), layout/frag-read = R13 proven conflict-free b128
//    (intra16 = lq*256+lm*16; .x -> MFMA ks=0, .y -> ks=1).
//  - Per K-tile: phase0 reads B (4 b128, persists) + A quadrant 0; phases
//    1-3 read A quadrants. 16 MFMA/phase = acc[2q..2q+1][0..3] x 2 ks.
//  - Staging: 32 units/tile / 8 waves = 4 loads/wave/tile, ONE per phase:
//    q=0: A unit wv; q=1: A wv+8; q=2: B wv; q=3: B wv+8. Tile kt+2 ->
//    buf (kt+2)%3 (= tile kt-1's buf; all waves past those reads at the
//    barrier preceding any stage issue -> race-free, R12 argument).
//  - vmcnt guard at each tile's phase 3 (before closing barrier):
//    kt<KITERS-2 -> vmcnt(4) (newest 4 = tile kt+2's); else vmcnt(0).
// Same fp8 values + per-acc K-order -> absmax 0.5.
// Predict: gemm ~40-47 us, MfmaUtil 45-55, total ~133-140.
// Falsifiers: fail -> race -> revert R14; flat ~59 -> pivot to non-gemm.

#define BQ 2048
#define DD 768
#define NPASS 8
#define PP 16384
#define BM 256
#define BN 256
#define BK 64
#define KITERS 12          // 768/64
#define NBLK 64            // PP/BN
#define MBLK 8             // BQ/BM
#define NCHUNKS 256        // NBLK * 4 n-waves

#define ALPHA_C 2.6f
#define INV_2SIG2 (1.0f/6.48f)   // 1/(2*1.8^2)

typedef __attribute__((ext_vector_type(4))) float floatx4;  // MFMA C/D
typedef __attribute__((ext_vector_type(2))) long longx2;    // ds_read_b128

// ---------------------------------------------------------------------------
// Kernel 1 (fused): cast q,p -> fp8 e4m3  +  s_t exact-fp32 dots  +  out=0.
// (unchanged)
// ---------------------------------------------------------------------------
#define NQ8   196608     // 2048*768/8
#define NTOT8 1769472    // (2048+16384)*768/8
#define NCB   6912       // NTOT8/256
__global__ __launch_bounds__(256) void prep_kernel(const float* __restrict__ qf,
                                                   const float* __restrict__ pf,
                                                   uint2* __restrict__ qb,
                                                   uint2* __restrict__ pb,
                                                   float* __restrict__ st,
                                                   float* __restrict__ out) {
  const int b = blockIdx.x;
  if (b == 0 && threadIdx.x == 0) *out = 0.f;
  if (b < NCB) {
    const int i = b * 256 + threadIdx.x;        // float8 index
    const float4* src; uint2* dst;
    if (i < NQ8) { src = (const float4*)qf + 2 * (size_t)i; dst = qb + i; }
    else { const size_t j = (size_t)i - NQ8; src = (const float4*)pf + 2 * j; dst = pb + j; }
    const float4 a = src[0], c = src[1];
    unsigned lo = __builtin_amdgcn_cvt_pk_fp8_f32(a.x, a.y, 0, 0);
    lo = __builtin_amdgcn_cvt_pk_fp8_f32(a.z, a.w, lo, 1);
    unsigned hi = __builtin_amdgcn_cvt_pk_fp8_f32(c.x, c.y, 0, 0);
    hi = __builtin_amdgcn_cvt_pk_fp8_f32(c.z, c.w, hi, 1);
    uint2 w; w.x = lo; w.y = hi;
    *dst = w;
  } else {
    const int wv = threadIdx.x >> 6, lane = threadIdx.x & 63;
    const int qi = (b - NCB) * 4 + wv;
    const float4* q4 = (const float4*)(qf + (size_t)qi * DD);
    const float4* p4 = (const float4*)(pf + (size_t)qi * NPASS * DD);
    float acc = 0.f;
#pragma unroll
    for (int u = 0; u < 3; ++u) {   // 192 float4 per row = 64 lanes * 3
      float4 a = q4[lane + 64 * u];
      float4 c = p4[lane + 64 * u];
      acc = fmaf(a.x, c.x, acc);
      acc = fmaf(a.y, c.y, acc);
      acc = fmaf(a.z, c.z, acc);
      acc = fmaf(a.w, c.w, acc);
    }
#pragma unroll
    for (int off = 32; off >= 1; off >>= 1) acc += __shfl_xor(acc, off);
    if (lane == 0) st[qi] = acc;
  }
}

// ---------------------------------------------------------------------------
// Kernel 2: fp8 MFMA GEMM 256x256, BK=64, 8-phase schedule (4 phases/K-tile),
// triple-buffered, counted vmcnt once per K-tile, setprio around MFMA.
// ---------------------------------------------------------------------------
__global__ __launch_bounds__(512, 2) void gemm_kernel(const unsigned char* __restrict__ qb,
                                                      const unsigned char* __restrict__ pb,
                                                      const float* __restrict__ st,
                                                      float* __restrict__ pm,
                                                      float* __restrict__ pl,
                                                      float* __restrict__ pc) {
  __shared__ unsigned char As[3][16 * 1024];   // 48 KB
  __shared__ unsigned char Bs[3][16 * 1024];   // 48 KB
  __shared__ float st_lds[BM];

  const int t = threadIdx.x;
  const int lane = t & 63;
  const int wv = t >> 6;            // 0..7
  const int wm = wv >> 2, wn = wv & 3;   // wm 0..1 (128 rows), wn 0..3 (64 cols)
  const int bid = blockIdx.x;       // 0..511
  const int xcd = bid & 7;          // round-robin XCD assignment
  const int nb = xcd * 8 + ((bid >> 3) & 7);   // XCD-private pb slice (1.5 MB)
  const int mb = bid >> 6;          // 0..7
  const int qbase = mb * BM;
  const int n0 = nb * BN;
  const int lm = lane & 15;
  const int lq = lane >> 4;
  const int lds_lane = lane * 16;

  if (t < BM) st_lds[t] = st[qbase + t];

  floatx4 acc[8][4];
#pragma unroll
  for (int i = 0; i < 8; ++i)
#pragma unroll
    for (int j = 0; j < 4; ++j) acc[i][j] = (floatx4){0.f, 0.f, 0.f, 0.f};

  // staging rows: wave wv stages A units {wv, wv+8}, B units {wv, wv+8}
  const size_t arowA = (size_t)(qbase + wv * 16 + lm) * DD;         // A unit wv
  const size_t arowB = arowA + (size_t)128 * DD;                    // A unit wv+8
  const size_t browA = (size_t)(n0 + wv * 16 + lm) * DD;            // B unit wv
  const size_t browB = browA + (size_t)128 * DD;                    // B unit wv+8
  const int intra16 = lq * 256 + lm * 16;      // conflict-free b128 (R13)

#define STAGE_A0(KT, BUF)                                                       \
  __builtin_amdgcn_global_load_lds(                                             \
      (const __attribute__((address_space(1))) void*)(qb + arowA + (size_t)(KT) * BK + lq * 16), \
      (__attribute__((address_space(3))) void*)(&As[BUF][wv * 1024] + lds_lane), 16, 0, 0);
#define STAGE_A1(KT, BUF)                                                       \
  __builtin_amdgcn_global_load_lds(                                             \
      (const __attribute__((address_space(1))) void*)(qb + arowB + (size_t)(KT) * BK + lq * 16), \
      (__attribute__((address_space(3))) void*)(&As[BUF][(wv + 8) * 1024] + lds_lane), 16, 0, 0);
#define STAGE_B0(KT, BUF)                                                       \
  __builtin_amdgcn_global_load_lds(                                             \
      (const __attribute__((address_space(1))) void*)(pb + browA + (size_t)(KT) * BK + lq * 16), \
      (__attribute__((address_space(3))) void*)(&Bs[BUF][wv * 1024] + lds_lane), 16, 0, 0);
#define STAGE_B1(KT, BUF)                                                       \
  __builtin_amdgcn_global_load_lds(                                             \
      (const __attribute__((address_space(1))) void*)(pb + browB + (size_t)(KT) * BK + lq * 16), \
      (__attribute__((address_space(3))) void*)(&Bs[BUF][(wv + 8) * 1024] + lds_lane), 16, 0, 0);

  // 16 MFMAs of quadrant Q: acc[2Q..2Q+1][0..3], ks=0 (.x) then ks=1 (.y);
  // same-acc pair spaced 8 apart.
#define MFMA16(Q)                                                               \
  {                                                                             \
    acc[2*Q+0][0] = __builtin_amdgcn_mfma_f32_16x16x32_fp8_fp8(a2[0].x, b2[0].x, acc[2*Q+0][0], 0, 0, 0); \
    acc[2*Q+0][1] = __builtin_amdgcn_mfma_f32_16x16x32_fp8_fp8(a2[0].x, b2[1].x, acc[2*Q+0][1], 0, 0, 0); \
    acc[2*Q+0][2] = __builtin_amdgcn_mfma_f32_16x16x32_fp8_fp8(a2[0].x, b2[2].x, acc[2*Q+0][2], 0, 0, 0); \
    acc[2*Q+0][3] = __builtin_amdgcn_mfma_f32_16x16x32_fp8_fp8(a2[0].x, b2[3].x, acc[2*Q+0][3], 0, 0, 0); \
    acc[2*Q+1][0] = __builtin_amdgcn_mfma_f32_16x16x32_fp8_fp8(a2[1].x, b2[0].x, acc[2*Q+1][0], 0, 0, 0); \
    acc[2*Q+1][1] = __builtin_amdgcn_mfma_f32_16x16x32_fp8_fp8(a2[1].x, b2[1].x, acc[2*Q+1][1], 0, 0, 0); \
    acc[2*Q+1][2] = __builtin_amdgcn_mfma_f32_16x16x32_fp8_fp8(a2[1].x, b2[2].x, acc[2*Q+1][2], 0, 0, 0); \
    acc[2*Q+1][3] = __builtin_amdgcn_mfma_f32_16x16x32_fp8_fp8(a2[1].x, b2[3].x, acc[2*Q+1][3], 0, 0, 0); \
    acc[2*Q+0][0] = __builtin_amdgcn_mfma_f32_16x16x32_fp8_fp8(a2[0].y, b2[0].y, acc[2*Q+0][0], 0, 0, 0); \
    acc[2*Q+0][1] = __builtin_amdgcn_mfma_f32_16x16x32_fp8_fp8(a2[0].y, b2[1].y, acc[2*Q+0][1], 0, 0, 0); \
    acc[2*Q+0][2] = __builtin_amdgcn_mfma_f32_16x16x32_fp8_fp8(a2[0].y, b2[2].y, acc[2*Q+0][2], 0, 0, 0); \
    acc[2*Q+0][3] = __builtin_amdgcn_mfma_f32_16x16x32_fp8_fp8(a2[0].y, b2[3].y, acc[2*Q+0][3], 0, 0, 0); \
    acc[2*Q+1][0] = __builtin_amdgcn_mfma_f32_16x16x32_fp8_fp8(a2[1].y, b2[0].y, acc[2*Q+1][0], 0, 0, 0); \
    acc[2*Q+1][1] = __builtin_amdgcn_mfma_f32_16x16x32_fp8_fp8(a2[1].y, b2[1].y, acc[2*Q+1][1], 0, 0, 0); \
    acc[2*Q+1][2] = __builtin_amdgcn_mfma_f32_16x16x32_fp8_fp8(a2[1].y, b2[2].y, acc[2*Q+1][2], 0, 0, 0); \
    acc[2*Q+1][3] = __builtin_amdgcn_mfma_f32_16x16x32_fp8_fp8(a2[1].y, b2[3].y, acc[2*Q+1][3], 0, 0, 0); \
  }

  // One phase: read A quadrant (+B in phase 0) || stage 1 load || bar ||
  // lgkmcnt(0) || setprio MFMA16 || [vmcnt guard if Q==3] || bar.
#define PHASE(Q, STAGE_STMT)                                                    \
  {                                                                             \
    if (Q == 0) {                                                               \
      b2[0] = *(const longx2*)(&Bs[cur][(wn * 4 + 0) * 1024] + intra16);        \
      b2[1] = *(const longx2*)(&Bs[cur][(wn * 4 + 1) * 1024] + intra16);        \
      b2[2] = *(const longx2*)(&Bs[cur][(wn * 4 + 2) * 1024] + intra16);        \
      b2[3] = *(const longx2*)(&Bs[cur][(wn * 4 + 3) * 1024] + intra16);        \
    }                                                                           \
    a2[0] = *(const longx2*)(&As[cur][(wm * 8 + 2 * Q + 0) * 1024] + intra16);  \
    a2[1] = *(const longx2*)(&As[cur][(wm * 8 + 2 * Q + 1) * 1024] + intra16);  \
    if (kt < KITERS - 2) { STAGE_STMT }                                         \
    __builtin_amdgcn_s_barrier();                                               \
    asm volatile("s_waitcnt lgkmcnt(0)" ::: "memory");                          \
    __builtin_amdgcn_sched_barrier(0);                                          \
    __builtin_amdgcn_s_setprio(1);                                              \
    MFMA16(Q)                                                                   \
    __builtin_amdgcn_s_setprio(0);                                              \
    if (Q == 3) {                                                               \
      if (kt < KITERS - 2) { asm volatile("s_waitcnt vmcnt(4)" ::: "memory"); } \
      else                 { asm volatile("s_waitcnt vmcnt(0)" ::: "memory"); } \
    }                                                                           \
    __builtin_amdgcn_s_barrier();                                               \
  }

  // prologue: stage tiles 0 and 1 fully; guard tile 0; enter loop
  STAGE_A0(0, 0) STAGE_A1(0, 0) STAGE_B0(0, 0) STAGE_B1(0, 0)
  STAGE_A0(1, 1) STAGE_A1(1, 1) STAGE_B0(1, 1) STAGE_B1(1, 1)
  asm volatile("s_waitcnt vmcnt(4)" ::: "memory");   // tile 0 done
  __builtin_amdgcn_s_barrier();

  int cur = 0;            // buffer holding K-tile kt
  int stg = 2;            // buffer for K-tile kt+2
  for (int kt = 0; kt < KITERS; ++kt) {
    longx2 a2[2], b2[4];
    PHASE(0, STAGE_A0(kt + 2, stg))
    PHASE(1, STAGE_A1(kt + 2, stg))
    PHASE(2, STAGE_B0(kt + 2, stg))
    PHASE(3, STAGE_B1(kt + 2, stg))
    cur = (cur == 2) ? 0 : cur + 1;
    stg = (stg == 2) ? 0 : stg + 1;
  }

  // ---- fused epilogue: per-row (query) max / sumexp / count over 64 cols ----
  // Chunk-major partials (proven R11): one 64B line per (wave,i) store group.
  const int chunk = nb * 4 + wn;
  float* const pmc = pm + (size_t)chunk * BQ;
  float* const plc = pl + (size_t)chunk * BQ;
  float* const pcc = pc + (size_t)chunk * BQ;
#pragma unroll
  for (int i = 0; i < 8; ++i) {
#pragma unroll
    for (int r = 0; r < 4; ++r) {
      const int rl = wm * 128 + i * 16 + lq * 4 + r;   // local query row
      float mx = fmaxf(fmaxf(acc[i][0][r], acc[i][1][r]),
                       fmaxf(acc[i][2][r], acc[i][3][r]));
#pragma unroll
      for (int off = 1; off <= 8; off <<= 1) mx = fmaxf(mx, __shfl_xor(mx, off));
      const float stv = st_lds[rl];
      const int qg = qbase + rl;
      const int tcol = qg * NPASS;
      float sum = 0.f, c = 0.f;
#pragma unroll
      for (int j = 0; j < 4; ++j) {
        const float s = acc[i][j][r];
        sum += __expf(s - mx);
        const int cg = n0 + wn * 64 + j * 16 + lm;
        if (s > stv && cg != tcol) c += 1.f;
      }
#pragma unroll
      for (int off = 1; off <= 8; off <<= 1) {
        sum += __shfl_xor(sum, off);
        c += __shfl_xor(c, off);
      }
      if (lm == 0) {
        pmc[qg] = mx; plc[qg] = sum; pcc[qg] = c;
      }
    }
  }
}

// ---------------------------------------------------------------------------
// Kernel 3: merge 256 chunks/query (chunk-major partials), weighted CE, mean.
// (unchanged)
// ---------------------------------------------------------------------------
__global__ __launch_bounds__(256) void finalize_kernel(const float* __restrict__ st,
                                                       const float* __restrict__ pm,
                                                       const float* __restrict__ pl,
                                                       const float* __restrict__ pc,
                                                       float* __restrict__ out) {
  const int wv = threadIdx.x >> 6, lane = threadIdx.x & 63;
  const int q = blockIdx.x * 64 + lane;
  const int c0 = wv * 64;
  float m = -1e30f, l = 0.f, c = 0.f;
#pragma unroll 4
  for (int ch = 0; ch < 64; ++ch) {
    const size_t idx = (size_t)(c0 + ch) * BQ + q;
    const float mv = pm[idx], lv = pl[idx], cv = pc[idx];
    const float nm = fmaxf(m, mv);
    l = l * __expf(m - nm) + lv * __expf(mv - nm);
    m = nm; c += cv;
  }
  __shared__ float sm[4][64], sl[4][64], sc[4][64];
  sm[wv][lane] = m; sl[wv][lane] = l; sc[wv][lane] = c;
  __syncthreads();
  if (wv == 0) {
    float M = sm[0][lane], L = sl[0][lane], C = sc[0][lane];
#pragma unroll
    for (int w = 1; w < 4; ++w) {
      const float mv = sm[w][lane];
      const float nm = fmaxf(M, mv);
      L = L * __expf(M - nm) + sl[w][lane] * __expf(mv - nm);
      M = nm; C += sc[w][lane];
    }
    const float raw = logf(L) + M - st[q];     // -log_softmax[target]
    const float dr = C - 1.0f;                 // rank - OPTIMAL_RANK
    const float w = 1.0f + ALPHA_C * __expf(-(dr * dr) * INV_2SIG2);
    float loss = raw * w * (1.0f / (float)BQ);
#pragma unroll
    for (int off = 32; off >= 1; off >>= 1) loss += __shfl_xor(loss, off);
    if (lane == 0) atomicAdd(out, loss);
  }
}

// ---------------------------------------------------------------------------
extern "C" void kernel_launch(void* const* d_in, const int* in_sizes, int n_in,
                              void* d_out, int out_size, void* d_ws, size_t ws_size,
                              hipStream_t stream) {
  const float* q = (const float*)d_in[0];
  const float* p = (const float*)d_in[1];
  char* ws = (char*)d_ws;
  unsigned char* qb = (unsigned char*)ws;                  // 1,572,864 B
  unsigned char* pb = (unsigned char*)(ws + 1572864);      // 12,582,912 B
  float* st = (float*)(ws + 14155776);                     // 8 KB
  float* pm = (float*)(ws + 14163968);                     // 2 MB
  float* pl = (float*)(ws + 16261120);                     // 2 MB
  float* pc = (float*)(ws + 18358272);                     // 2 MB (end ~20.5 MB)
  float* out = (float*)d_out;

  prep_kernel<<<NCB + BQ / 4, 256, 0, stream>>>(q, p, (uint2*)qb, (uint2*)pb, st, out);
  gemm_kernel<<<NBLK * MBLK, 512, 0, stream>>>(qb, pb, st, pm, pl, pc);
  finalize_kernel<<<BQ / 64, 256, 0, stream>>>(st, pm, pl, pc, out);
}

// Round 17
// 146.688 us; speedup vs baseline: 1.1249x; 1.1249x over previous
//
#include <hip/hip_runtime.h>
#include <math.h>

// Problem: scores = q[2048x768] @ p[16384x768]^T (fp32 in), per-query
// rank-of-target + log-softmax CE + Gaussian rank weight -> mean (scalar).
// R18: decomposition round. R17 8-phase REGRESSED (71.6 us, MfmaUtil 27):
// doubled barriers at 2 waves/SIMD. Gemm structural levers exhausted
// (R12 +17%, R13/R14/R16 null, R17 -22%) -> R14 (58.9us) = gemm plateau.
// Non-gemm = total - gemm ~= 94 us every round, invisible in top-5.
// This round: gemm = R14 VERBATIM; attack prep + finalize:
//  - prep: 16 floats/thread (4xfloat4 -> one uint4 store, 16B/lane
//    coalescing sweet spot), same cvt_pk ops -> identical fp8 bytes.
//  - finalize 2-stage: stage A 256 blocks (8x parallelism, 8-deep merge)
//    -> 8 slice-partials/query in pm2/pl2/pc2; stage B 32 blocks x 1 wave
//    merges 8 slices, CE + Gaussian weight + atomicAdd.
// Predict: gemm unchanged (58.9, MfmaUtil 33); total 152.8 -> ~125-138 if
// non-gemm was kernel time; flat ~150 -> it's launch/harness overhead and
// kernels are at practical floor. absmax 0.5 (scores bit-identical).

#define BQ 2048
#define DD 768
#define NPASS 8
#define PP 16384
#define BM 256
#define BN 256
#define BK 64
#define KITERS 12          // 768/64
#define NBLK 64            // PP/BN
#define MBLK 8             // BQ/BM
#define NCHUNKS 256        // NBLK * 4 n-waves

#define ALPHA_C 2.6f
#define INV_2SIG2 (1.0f/6.48f)   // 1/(2*1.8^2)

typedef __attribute__((ext_vector_type(4))) float floatx4;  // MFMA C/D
typedef __attribute__((ext_vector_type(2))) long longx2;    // ds_read_b128

// ---------------------------------------------------------------------------
// Kernel 1 (fused): cast q,p -> fp8 e4m3 (16 floats/thread, uint4 stores)
// + s_t exact-fp32 dots + out=0.
// ---------------------------------------------------------------------------
#define NQ16   98304     // 2048*768/16
#define NTOT16 884736    // (2048+16384)*768/16
#define NCB16  3456      // NTOT16/256
__global__ __launch_bounds__(256) void prep_kernel(const float* __restrict__ qf,
                                                   const float* __restrict__ pf,
                                                   uint4* __restrict__ qb,
                                                   uint4* __restrict__ pb,
                                                   float* __restrict__ st,
                                                   float* __restrict__ out) {
  const int b = blockIdx.x;
  if (b == 0 && threadIdx.x == 0) *out = 0.f;
  if (b < NCB16) {
    const int i = b * 256 + threadIdx.x;        // 16-float unit index
    const float4* src; uint4* dst;
    if (i < NQ16) { src = (const float4*)qf + 4 * (size_t)i; dst = qb + i; }
    else { const size_t j = (size_t)i - NQ16; src = (const float4*)pf + 4 * j; dst = pb + j; }
    const float4 v0 = src[0], v1 = src[1], v2 = src[2], v3 = src[3];
    unsigned u0 = __builtin_amdgcn_cvt_pk_fp8_f32(v0.x, v0.y, 0, 0);
    u0 = __builtin_amdgcn_cvt_pk_fp8_f32(v0.z, v0.w, u0, 1);
    unsigned u1 = __builtin_amdgcn_cvt_pk_fp8_f32(v1.x, v1.y, 0, 0);
    u1 = __builtin_amdgcn_cvt_pk_fp8_f32(v1.z, v1.w, u1, 1);
    unsigned u2 = __builtin_amdgcn_cvt_pk_fp8_f32(v2.x, v2.y, 0, 0);
    u2 = __builtin_amdgcn_cvt_pk_fp8_f32(v2.z, v2.w, u2, 1);
    unsigned u3 = __builtin_amdgcn_cvt_pk_fp8_f32(v3.x, v3.y, 0, 0);
    u3 = __builtin_amdgcn_cvt_pk_fp8_f32(v3.z, v3.w, u3, 1);
    uint4 w; w.x = u0; w.y = u1; w.z = u2; w.w = u3;
    *dst = w;
  } else {
    const int wv = threadIdx.x >> 6, lane = threadIdx.x & 63;
    const int qi = (b - NCB16) * 4 + wv;
    const float4* q4 = (const float4*)(qf + (size_t)qi * DD);
    const float4* p4 = (const float4*)(pf + (size_t)qi * NPASS * DD);
    float acc = 0.f;
#pragma unroll
    for (int u = 0; u < 3; ++u) {   // 192 float4 per row = 64 lanes * 3
      float4 a = q4[lane + 64 * u];
      float4 c = p4[lane + 64 * u];
      acc = fmaf(a.x, c.x, acc);
      acc = fmaf(a.y, c.y, acc);
      acc = fmaf(a.z, c.z, acc);
      acc = fmaf(a.w, c.w, acc);
    }
#pragma unroll
    for (int off = 32; off >= 1; off >>= 1) acc += __shfl_xor(acc, off);
    if (lane == 0) st[qi] = acc;
  }
}

// ---------------------------------------------------------------------------
// Kernel 2: fp8 MFMA GEMM 256x256, BK=64, TRIPLE-buffered global_load_lds
// with counted vmcnt = R14 VERBATIM (best measured: 58.9 us, MfmaUtil 33,
// conflicts 0). 16 waves (4m x 4n), wave = 64x64 out (4x4 of 16x16x32).
// LDS unit = 16 rows x 64 k-bytes = 1 KB; conflict-free b128 K-permuted
// frag reads (intra16 = lq*256+lm*16; .x -> MFMA ks=0, .y -> ks=1).
// C/D: col=lane&15, row=(lane>>4)*4+reg.
// ---------------------------------------------------------------------------
__global__ __launch_bounds__(1024) void gemm_kernel(const unsigned char* __restrict__ qb,
                                                    const unsigned char* __restrict__ pb,
                                                    const float* __restrict__ st,
                                                    float* __restrict__ pm,
                                                    float* __restrict__ pl,
                                                    float* __restrict__ pc) {
  __shared__ unsigned char As[3][16 * 1024];   // 48 KB
  __shared__ unsigned char Bs[3][16 * 1024];   // 48 KB
  __shared__ float st_lds[BM];

  const int t = threadIdx.x;
  const int lane = t & 63;
  const int wv = t >> 6;            // 0..15
  const int wm = wv >> 2, wn = wv & 3;
  const int bid = blockIdx.x;       // 0..511
  const int xcd = bid & 7;          // round-robin XCD assignment
  const int nb = xcd * 8 + ((bid >> 3) & 7);   // XCD-private pb slice (1.5 MB)
  const int mb = bid >> 6;          // 0..7
  const int qbase = mb * BM;
  const int n0 = nb * BN;
  const int lm = lane & 15;
  const int lq = lane >> 4;
  const int lds_lane = lane * 16;

  if (t < BM) st_lds[t] = st[qbase + t];

  floatx4 acc[4][4];
#pragma unroll
  for (int i = 0; i < 4; ++i)
#pragma unroll
    for (int j = 0; j < 4; ++j) acc[i][j] = (floatx4){0.f, 0.f, 0.f, 0.f};

  const size_t arow = (size_t)(qbase + wv * 16 + lm) * DD;
  const size_t brow = (size_t)(n0 + wv * 16 + lm) * DD;
  const int intra16 = lq * 256 + lm * 16;      // one 16-B chunk per lane

#define STAGE(KT, BUF)                                                          \
  {                                                                             \
    const size_t koff = (size_t)(KT) * BK + lq * 16;                            \
    __builtin_amdgcn_global_load_lds(                                           \
        (const __attribute__((address_space(1))) void*)(qb + arow + koff),      \
        (__attribute__((address_space(3))) void*)(&As[BUF][wv * 1024] + lds_lane), \
        16, 0, 0);                                                              \
    __builtin_amdgcn_global_load_lds(                                           \
        (const __attribute__((address_space(1))) void*)(pb + brow + koff),      \
        (__attribute__((address_space(3))) void*)(&Bs[BUF][wv * 1024] + lds_lane), \
        16, 0, 0);                                                              \
  }

#define MFMA8(II, JJ)                                                           \
  {                                                                             \
    acc[II][JJ]       = __builtin_amdgcn_mfma_f32_16x16x32_fp8_fp8(a2[II].x,     b2[JJ].x,     acc[II][JJ],       0, 0, 0); \
    acc[II][JJ+1]     = __builtin_amdgcn_mfma_f32_16x16x32_fp8_fp8(a2[II].x,     b2[JJ+1].x,   acc[II][JJ+1],     0, 0, 0); \
    acc[II+1][JJ]     = __builtin_amdgcn_mfma_f32_16x16x32_fp8_fp8(a2[II+1].x,   b2[JJ].x,     acc[II+1][JJ],     0, 0, 0); \
    acc[II+1][JJ+1]   = __builtin_amdgcn_mfma_f32_16x16x32_fp8_fp8(a2[II+1].x,   b2[JJ+1].x,   acc[II+1][JJ+1],   0, 0, 0); \
    acc[II][JJ]       = __builtin_amdgcn_mfma_f32_16x16x32_fp8_fp8(a2[II].y,     b2[JJ].y,     acc[II][JJ],       0, 0, 0); \
    acc[II][JJ+1]     = __builtin_amdgcn_mfma_f32_16x16x32_fp8_fp8(a2[II].y,     b2[JJ+1].y,   acc[II][JJ+1],     0, 0, 0); \
    acc[II+1][JJ]     = __builtin_amdgcn_mfma_f32_16x16x32_fp8_fp8(a2[II+1].y,   b2[JJ].y,     acc[II+1][JJ],     0, 0, 0); \
    acc[II+1][JJ+1]   = __builtin_amdgcn_mfma_f32_16x16x32_fp8_fp8(a2[II+1].y,   b2[JJ+1].y,   acc[II+1][JJ+1],   0, 0, 0); \
  }

#define COMPUTE(CB)                                                             \
  {                                                                             \
    longx2 a2[4], b2[4];                                                        \
    a2[0] = *(const longx2*)(&As[CB][(wm * 4 + 0) * 1024] + intra16);           \
    a2[1] = *(const longx2*)(&As[CB][(wm * 4 + 1) * 1024] + intra16);           \
    b2[0] = *(const longx2*)(&Bs[CB][(wn * 4 + 0) * 1024] + intra16);           \
    b2[1] = *(const longx2*)(&Bs[CB][(wn * 4 + 1) * 1024] + intra16);           \
    __builtin_amdgcn_sched_barrier(0);                                          \
    b2[2] = *(const longx2*)(&Bs[CB][(wn * 4 + 2) * 1024] + intra16);           \
    b2[3] = *(const longx2*)(&Bs[CB][(wn * 4 + 3) * 1024] + intra16);           \
    __builtin_amdgcn_sched_barrier(0);                                          \
    __builtin_amdgcn_s_setprio(1);                                              \
    MFMA8(0, 0)                                                                 \
    __builtin_amdgcn_s_setprio(0);                                              \
    __builtin_amdgcn_sched_barrier(0);                                          \
    a2[2] = *(const longx2*)(&As[CB][(wm * 4 + 2) * 1024] + intra16);           \
    a2[3] = *(const longx2*)(&As[CB][(wm * 4 + 3) * 1024] + intra16);           \
    __builtin_amdgcn_sched_barrier(0);                                          \
    __builtin_amdgcn_s_setprio(1);                                              \
    MFMA8(0, 2)                                                                 \
    __builtin_amdgcn_s_setprio(0);                                              \
    __builtin_amdgcn_sched_barrier(0);                                          \
    __builtin_amdgcn_s_setprio(1);                                              \
    MFMA8(2, 0)                                                                 \
    MFMA8(2, 2)                                                                 \
    __builtin_amdgcn_s_setprio(0);                                              \
  }

  STAGE(0, 0)
  STAGE(1, 1)
  int cur = 0;            // buffer holding K-tile kt
  int stg = 2;            // buffer to stage K-tile kt+2 into
  for (int kt = 0; kt < KITERS - 1; ++kt) {
    asm volatile("s_waitcnt vmcnt(2)" ::: "memory");
    __builtin_amdgcn_s_barrier();
    __builtin_amdgcn_sched_barrier(0);
    if (kt < KITERS - 2) STAGE(kt + 2, stg)
    COMPUTE(cur)
    cur = (cur == 2) ? 0 : cur + 1;
    stg = (stg == 2) ? 0 : stg + 1;
  }
  asm volatile("s_waitcnt vmcnt(0)" ::: "memory");
  __builtin_amdgcn_s_barrier();
  __builtin_amdgcn_sched_barrier(0);
  COMPUTE(cur)

  // ---- fused epilogue: chunk-major partials (proven R11) ----
  const int chunk = nb * 4 + wn;
  float* const pmc = pm + (size_t)chunk * BQ;
  float* const plc = pl + (size_t)chunk * BQ;
  float* const pcc = pc + (size_t)chunk * BQ;
#pragma unroll
  for (int i = 0; i < 4; ++i) {
#pragma unroll
    for (int r = 0; r < 4; ++r) {
      const int rl = wm * 64 + i * 16 + lq * 4 + r;   // local query row
      float mx = fmaxf(fmaxf(acc[i][0][r], acc[i][1][r]),
                       fmaxf(acc[i][2][r], acc[i][3][r]));
#pragma unroll
      for (int off = 1; off <= 8; off <<= 1) mx = fmaxf(mx, __shfl_xor(mx, off));
      const float stv = st_lds[rl];
      const int qg = qbase + rl;
      const int tcol = qg * NPASS;
      float sum = 0.f, c = 0.f;
#pragma unroll
      for (int j = 0; j < 4; ++j) {
        const float s = acc[i][j][r];
        sum += __expf(s - mx);
        const int cg = n0 + wn * 64 + j * 16 + lm;
        if (s > stv && cg != tcol) c += 1.f;
      }
#pragma unroll
      for (int off = 1; off <= 8; off <<= 1) {
        sum += __shfl_xor(sum, off);
        c += __shfl_xor(c, off);
      }
      if (lm == 0) {
        pmc[qg] = mx; plc[qg] = sum; pcc[qg] = c;
      }
    }
  }
}

// ---------------------------------------------------------------------------
// Kernel 3a (stage A): merge chunks 32-at-a-time. 256 blocks x 256 thr.
// Block b: queries (b&31)*64..+63, slice b>>5 (chunks slice*32..+31).
// Wave wv merges 8 chunks (lane = query); LDS-merge 4 waves; wave 0 stores
// pm2/pl2/pc2[slice*BQ + q] (coalesced).
// ---------------------------------------------------------------------------
__global__ __launch_bounds__(256) void merge_kernel(const float* __restrict__ pm,
                                                    const float* __restrict__ pl,
                                                    const float* __restrict__ pc,
                                                    float* __restrict__ pm2,
                                                    float* __restrict__ pl2,
                                                    float* __restrict__ pc2) {
  const int wv = threadIdx.x >> 6, lane = threadIdx.x & 63;
  const int q = (blockIdx.x & 31) * 64 + lane;
  const int slice = blockIdx.x >> 5;
  const int c0 = slice * 32 + wv * 8;
  float m = -1e30f, l = 0.f, c = 0.f;
#pragma unroll
  for (int ch = 0; ch < 8; ++ch) {
    const size_t idx = (size_t)(c0 + ch) * BQ + q;
    const float mv = pm[idx], lv = pl[idx], cv = pc[idx];
    const float nm = fmaxf(m, mv);
    l = l * __expf(m - nm) + lv * __expf(mv - nm);
    m = nm; c += cv;
  }
  __shared__ float sm[4][64], sl[4][64], sc[4][64];
  sm[wv][lane] = m; sl[wv][lane] = l; sc[wv][lane] = c;
  __syncthreads();
  if (wv == 0) {
    float M = sm[0][lane], L = sl[0][lane], C = sc[0][lane];
#pragma unroll
    for (int w = 1; w < 4; ++w) {
      const float mv = sm[w][lane];
      const float nm = fmaxf(M, mv);
      L = L * __expf(M - nm) + sl[w][lane] * __expf(mv - nm);
      M = nm; C += sc[w][lane];
    }
    const size_t o = (size_t)slice * BQ + q;
    pm2[o] = M; pl2[o] = L; pc2[o] = C;
  }
}

// ---------------------------------------------------------------------------
// Kernel 3b (stage B): merge 8 slices/query, weighted CE, mean -> atomicAdd.
// 32 blocks x 64 thr (1 wave); lane = query (coalesced slice reads).
// ---------------------------------------------------------------------------
__global__ __launch_bounds__(64) void finalize_kernel(const float* __restrict__ st,
                                                      const float* __restrict__ pm2,
                                                      const float* __restrict__ pl2,
                                                      const float* __restrict__ pc2,
                                                      float* __restrict__ out) {
  const int lane = threadIdx.x;
  const int q = blockIdx.x * 64 + lane;
  float m = -1e30f, l = 0.f, c = 0.f;
#pragma unroll
  for (int s = 0; s < 8; ++s) {
    const size_t idx = (size_t)s * BQ + q;
    const float mv = pm2[idx], lv = pl2[idx], cv = pc2[idx];
    const float nm = fmaxf(m, mv);
    l = l * __expf(m - nm) + lv * __expf(mv - nm);
    m = nm; c += cv;
  }
  const float raw = logf(l) + m - st[q];       // -log_softmax[target]
  const float dr = c - 1.0f;                   // rank - OPTIMAL_RANK
  const float w = 1.0f + ALPHA_C * __expf(-(dr * dr) * INV_2SIG2);
  float loss = raw * w * (1.0f / (float)BQ);
#pragma unroll
  for (int off = 32; off >= 1; off >>= 1) loss += __shfl_xor(loss, off);
  if (lane == 0) atomicAdd(out, loss);
}

// ---------------------------------------------------------------------------
extern "C" void kernel_launch(void* const* d_in, const int* in_sizes, int n_in,
                              void* d_out, int out_size, void* d_ws, size_t ws_size,
                              hipStream_t stream) {
  const float* q = (const float*)d_in[0];
  const float* p = (const float*)d_in[1];
  char* ws = (char*)d_ws;
  unsigned char* qb = (unsigned char*)ws;                  // 1,572,864 B
  unsigned char* pb = (unsigned char*)(ws + 1572864);      // 12,582,912 B
  float* st = (float*)(ws + 14155776);                     // 8 KB
  float* pm = (float*)(ws + 14163968);                     // 2 MB
  float* pl = (float*)(ws + 16261120);                     // 2 MB
  float* pc = (float*)(ws + 18358272);                     // 2 MB
  float* pm2 = (float*)(ws + 20455424);                    // 64 KB
  float* pl2 = (float*)(ws + 20520960);                    // 64 KB
  float* pc2 = (float*)(ws + 20586496);                    // 64 KB (end ~20.7 MB)
  float* out = (float*)d_out;

  prep_kernel<<<NCB16 + BQ / 4, 256, 0, stream>>>(q, p, (uint4*)qb, (uint4*)pb, st, out);
  gemm_kernel<<<NBLK * MBLK, 1024, 0, stream>>>(qb, pb, st, pm, pl, pc);
  merge_kernel<<<256, 256, 0, stream>>>(pm, pl, pc, pm2, pl2, pc2);
  finalize_kernel<<<BQ / 64, 64, 0, stream>>>(st, pm2, pl2, pc2, out);
}